// Round 13
// baseline (371.726 us; speedup 1.0000x reference)
//
#include <hip/hip_runtime.h>
#include <hip/hip_fp16.h>
#include <math.h>

// Transformer-XL relative multi-head attention, MI355X. B=2,S=2048,D=512,H=8,dh=64.
// Round-13: Ppos tensor ELIMINATED (again, but in the r8+ swapped orientation that
// works). r12 diagnosis: attn bound by the 134 MB Ppos HBM stream (DMA got it to
// 1.26 TB/s but single-buffer serialization caps it), and pos_gemm spends ~as much
// writing it. Fix: per wave-tile, compute the rel-shifted pos scores IN-TILE:
//   shifted[q][k] = qv[q]  . Pb[2047-(q-k)]  (k<=q)   -> R1[ii][q], J1=2032-q0+k0
//                 = 0                         (k==q+1)
//                 = qv[q+1]. Pb[k-q-2]        (k>=q+2) -> R2[ii][q], J2=k0-q0-17
// with shared local index ii=(k-k0)-(q-q0)+15 in [0,143].  Each R side is a
// 144x16x64 MFMA GEMM (9x2 mfma) into wave-private LDS [q][ii] (stride 144);
// extraction = ds_read_u16 + select.  need-R1 (k0<=q0+15) / need-R2 (k0+127>=q0+2)
// are WAVE-UNIFORM; avg 1.06 sides/tile.  Pb is 4 MB/head -> L2-resident.
// Deletes: pos_gemm kernel, 134 MB Ppos write + read, DMA machinery, chunk loop.
// Pb/QV row over/under-runs (rows <0 / >2047 of a head) stay inside d_ws and are
// never selected.  launch_bounds(256,3): LDS (38.9 KB) caps at 3 blocks/CU anyway;
// 170-VGPR ceiling avoids r7's spill.
//  1. conv_inputs : x,pos fp32 -> fp16.   2. conv_wt: 5 weights -> fp16 W^T.
//  3. proj_mfma   : QU(+u)/QV(+v), K, Pb [s][d]; VT [d][s]  (fp16 MFMA).
//  4. attn_fused  : single launch, 16 heads x 128 q-tiles.
//  5. out_mfma    : out(fp32) = ctx @ Wo + bo.

#define S_LEN 2048
#define NH 8
#define DHD 64
#define DM 512
#define NBH 16
#define HEAD_ELEMS (S_LEN * DHD)

// workspace byte offsets
#define BY_QU  0u               // fp16 [16][2048][64]  4 MB
#define BY_QV  4194304u         // fp16 [16][2048][64]  4 MB
#define BY_K   8388608u         // fp16 [16][2048][64]  4 MB
#define BY_VT  12582912u        // fp16 [16][64][2048]  4 MB
#define BY_PB  16777216u        // fp16 [16][2048][64]  4 MB
#define BY_XH  20971520u        // fp16 [2][2048][512]  4 MB
#define BY_PH  25165824u        // fp16 [2][2048][512]  4 MB
#define BY_WT  29360128u        // fp16 [5][512][512] transposed, 2.62 MB
#define BY_CTX 31981568u        // fp16 [2][2048][512]  4 MB
#define WS_NEED 36175872u
#define WT_MAT_HALFS 262144u

typedef short v8s __attribute__((ext_vector_type(8)));
typedef float v4f __attribute__((ext_vector_type(4)));

static __device__ __forceinline__ unsigned short f2h(float f) {
    __half h = __float2half(f);
    return *reinterpret_cast<unsigned short*>(&h);
}
static __device__ __forceinline__ float h2f(unsigned short u) {
    __half h = *reinterpret_cast<__half*>(&u);
    return __half2float(h);
}

// ---------------------------------------------------------------------------
// conv_inputs: fp32 -> fp16, 4 els/thread. z: 0 = x, 1 = pos.
// ---------------------------------------------------------------------------
__global__ __launch_bounds__(256)
void conv_inputs(const float* __restrict__ x, const float* __restrict__ pos,
                 char* __restrict__ wsb)
{
    const float* src = blockIdx.z ? pos : x;
    unsigned short* dst = (unsigned short*)(wsb + (blockIdx.z ? BY_PH : BY_XH));
    int i = (blockIdx.x * 256 + threadIdx.x) * 4;
    float4 a = *(const float4*)(src + i);
    ushort4 p;
    p.x = f2h(a.x); p.y = f2h(a.y); p.z = f2h(a.z); p.w = f2h(a.w);
    *(ushort4*)(dst + i) = p;
}

// ---------------------------------------------------------------------------
// conv_wt: WT[m][n][k] = W_m[k][n] fp16. 64x64 LDS tile transpose.
// ---------------------------------------------------------------------------
__global__ __launch_bounds__(256)
void conv_wt(const float* __restrict__ Wq, const float* __restrict__ Wk,
             const float* __restrict__ Wv, const float* __restrict__ Wp,
             const float* __restrict__ Wo, char* __restrict__ wsb)
{
    __shared__ float T[64][65];
    const float* W = (blockIdx.z == 0) ? Wq : (blockIdx.z == 1) ? Wk :
                     (blockIdx.z == 2) ? Wv : (blockIdx.z == 3) ? Wp : Wo;
    unsigned short* WT = (unsigned short*)(wsb + BY_WT) + blockIdx.z * WT_MAT_HALFS;
    const int n0 = blockIdx.x * 64, k0 = blockIdx.y * 64;
    const int t = threadIdx.x;
#pragma unroll
    for (int i = 0; i < 4; ++i) {
        int f = t + i * 256;
        int row = f >> 4, c4 = f & 15;
        *(float4*)&T[row][c4 * 4] = *(const float4*)(W + (size_t)(k0 + row) * 512 + n0 + c4 * 4);
    }
    __syncthreads();
#pragma unroll
    for (int i = 0; i < 4; ++i) {
        int f = t + i * 256;
        int n = f >> 4, k4 = f & 15;
        ushort4 p;
        p.x = f2h(T[k4 * 4 + 0][n]); p.y = f2h(T[k4 * 4 + 1][n]);
        p.z = f2h(T[k4 * 4 + 2][n]); p.w = f2h(T[k4 * 4 + 3][n]);
        *(ushort4*)(WT + (size_t)(n0 + n) * 512 + k0 + k4 * 4) = p;
    }
}

// ---------------------------------------------------------------------------
// proj_mfma: all four projections via fp16 MFMA, no LDS, 4 waves = 2x2 64x64.
// modes 0(Q),1(K),3(P): SWAPPED C[d][s]; mode 2(V): C[s][d] -> VT store.
// ---------------------------------------------------------------------------
__global__ __launch_bounds__(256)
void proj_mfma(const float* __restrict__ bq, const float* __restrict__ bk,
               const float* __restrict__ bvp,
               const float* __restrict__ uvec, const float* __restrict__ vvec,
               char* __restrict__ wsb)
{
    const int t = threadIdx.x;
    const int wave = t >> 6, lane = t & 63;
    const int quad = lane >> 4, l16 = lane & 15;
    const int wm = wave >> 1, wn = wave & 1;
    const int mode = blockIdx.z;
    const unsigned short* xh = (const unsigned short*)(wsb + BY_XH);
    const unsigned short* ph = (const unsigned short*)(wsb + BY_PH);
    const unsigned short* wt = (const unsigned short*)(wsb + BY_WT);

    v4f acc[4][4];
#pragma unroll
    for (int i = 0; i < 4; ++i)
#pragma unroll
        for (int j = 0; j < 4; ++j) acc[i][j] = (v4f){0.f, 0.f, 0.f, 0.f};

    if (mode != 2) {
        const int d0 = blockIdx.y * 128 + wm * 64;
        const int s0 = blockIdx.x * 128 + wn * 64;
        const int mat = (mode == 0) ? 0 : (mode == 1) ? 1 : 3;
        const unsigned short* A = wt + (size_t)mat * WT_MAT_HALFS;   // [d][k]
        const unsigned short* B = (mode == 3) ? ph : xh;             // [s][k]

        for (int kk = 0; kk < 16; ++kk) {
            v8s af[4], bf[4];
#pragma unroll
            for (int i = 0; i < 4; ++i) {
                af[i] = *(const v8s*)(A + (size_t)(d0 + i * 16 + l16) * 512 + kk * 32 + quad * 8);
                bf[i] = *(const v8s*)(B + (size_t)(s0 + i * 16 + l16) * 512 + kk * 32 + quad * 8);
            }
#pragma unroll
            for (int i = 0; i < 4; ++i)
#pragma unroll
                for (int j = 0; j < 4; ++j)
                    acc[i][j] = __builtin_amdgcn_mfma_f32_16x16x32_f16(af[i], bf[j], acc[i][j], 0, 0, 0);
        }

#pragma unroll
        for (int i = 0; i < 4; ++i) {
            int db = d0 + i * 16 + quad * 4;
            int h = db >> 6, dl = db & 63;
            float4 b4 = (mode == 3) ? make_float4(0.f, 0.f, 0.f, 0.f)
                        : (mode == 0) ? *(const float4*)(bq + db)
                                      : *(const float4*)(bk + db);
#pragma unroll
            for (int j = 0; j < 4; ++j) {
                int s = s0 + j * 16 + l16;
                int bb = s >> 11, srow = s & 2047;
                size_t o = ((size_t)(bb * NH + h) * S_LEN + srow) * DHD + dl;
                if (mode == 0) {
                    float4 u4 = *(const float4*)(uvec + db);
                    float4 v4 = *(const float4*)(vvec + db);
                    unsigned short* qu = (unsigned short*)(wsb + BY_QU);
                    unsigned short* qv = (unsigned short*)(wsb + BY_QV);
                    ushort4 pu, pv;
                    pu.x = f2h(acc[i][j][0] + b4.x + u4.x);
                    pu.y = f2h(acc[i][j][1] + b4.y + u4.y);
                    pu.z = f2h(acc[i][j][2] + b4.z + u4.z);
                    pu.w = f2h(acc[i][j][3] + b4.w + u4.w);
                    pv.x = f2h(acc[i][j][0] + b4.x + v4.x);
                    pv.y = f2h(acc[i][j][1] + b4.y + v4.y);
                    pv.z = f2h(acc[i][j][2] + b4.z + v4.z);
                    pv.w = f2h(acc[i][j][3] + b4.w + v4.w);
                    *(ushort4*)(qu + o) = pu;
                    *(ushort4*)(qv + o) = pv;
                } else {
                    unsigned short* dst = (unsigned short*)(wsb + (mode == 1 ? BY_K : BY_PB));
                    ushort4 pk;
                    pk.x = f2h(acc[i][j][0] + b4.x);
                    pk.y = f2h(acc[i][j][1] + b4.y);
                    pk.z = f2h(acc[i][j][2] + b4.z);
                    pk.w = f2h(acc[i][j][3] + b4.w);
                    *(ushort4*)(dst + o) = pk;
                }
            }
        }
    } else {
        const int s0 = blockIdx.x * 128 + wm * 64;
        const int d0 = blockIdx.y * 128 + wn * 64;
        const unsigned short* A = xh;                                 // [s][k]
        const unsigned short* B = wt + (size_t)2 * WT_MAT_HALFS;      // [d][k]

        for (int kk = 0; kk < 16; ++kk) {
            v8s af[4], bf[4];
#pragma unroll
            for (int i = 0; i < 4; ++i) {
                af[i] = *(const v8s*)(A + (size_t)(s0 + i * 16 + l16) * 512 + kk * 32 + quad * 8);
                bf[i] = *(const v8s*)(B + (size_t)(d0 + i * 16 + l16) * 512 + kk * 32 + quad * 8);
            }
#pragma unroll
            for (int i = 0; i < 4; ++i)
#pragma unroll
                for (int j = 0; j < 4; ++j)
                    acc[i][j] = __builtin_amdgcn_mfma_f32_16x16x32_f16(af[i], bf[j], acc[i][j], 0, 0, 0);
        }

        unsigned short* vt = (unsigned short*)(wsb + BY_VT);
#pragma unroll
        for (int j = 0; j < 4; ++j) {
            int d = d0 + j * 16 + l16;
            int h = d >> 6, dl = d & 63;
            float bval = bvp[d];
#pragma unroll
            for (int i = 0; i < 4; ++i) {
                int sb = s0 + i * 16 + quad * 4;
                int bb = sb >> 11, srow = sb & 2047;
                size_t o = ((size_t)(bb * NH + h) * DHD + dl) * S_LEN + srow;
                ushort4 pk;
                pk.x = f2h(acc[i][j][0] + bval);
                pk.y = f2h(acc[i][j][1] + bval);
                pk.z = f2h(acc[i][j][2] + bval);
                pk.w = f2h(acc[i][j][3] + bval);
                *(ushort4*)(vt + o) = pk;
            }
        }
    }
}

// ---------------------------------------------------------------------------
// Flash attention with in-tile rel-shift GEMMs.  Single launch: grid =
// 16 heads x 128 q-tiles; block 256 = 4 waves; wave w owns keys [w*512,+512),
// 4 k-tiles of 128; barrier-free k-loop (wave-private LDS, in-order per wave).
// QK^T: A=K rows, B=QU rows -> C[key][q=l16]  (r8 layout).
// Pos:  R1[ii][q] = Pb[J1+ii].qv[q]   (covers k<=q),   J1 = 2032-q0+k0
//       R2[ii][q] = Pb[J2+ii].qv[q+1] (covers k>=q+2), J2 = k0-q0-17
//       ii = (k-k0)-(q-q0)+15; extraction ds_read_u16 from [q][ii] stride 144.
// need1/need2 are wave-uniform.  Sp (P-transpose) aliases R1L after extraction.
// ---------------------------------------------------------------------------
__global__ __launch_bounds__(256, 3)
void attn_fused(const unsigned short* __restrict__ qu,
                const unsigned short* __restrict__ qvg,
                const unsigned short* __restrict__ kdat,
                const unsigned short* __restrict__ vtg,
                const unsigned short* __restrict__ pbg,
                unsigned short* __restrict__ ctx)
{
    __shared__ unsigned short RAll[4][4608];   // per wave: R1L[0..2303] R2L[2304..]
    __shared__ float MlAll[4][128];

    const int t = threadIdx.x;
    const int wave = t >> 6, lane = t & 63;
    const int quad = lane >> 4, l16 = lane & 15;
    const int z = blockIdx.x >> 7, qt = blockIdx.x & 127;
    const int q0 = qt * 16;
    const int q = q0 + l16;

    const unsigned short* QU = qu   + (size_t)z * HEAD_ELEMS;
    const unsigned short* QV = qvg  + (size_t)z * HEAD_ELEMS;
    const unsigned short* Kg = kdat + (size_t)z * HEAD_ELEMS;
    const unsigned short* Vg = vtg  + (size_t)z * HEAD_ELEMS;
    const unsigned short* Pb = pbg  + (size_t)z * HEAD_ELEMS;
    unsigned short* R1L = &RAll[wave][0];
    unsigned short* R2L = &RAll[wave][2304];
    unsigned short* Sp  = &RAll[wave][0];      // aliases R1L (post-extraction)

    // persistent B-operand fragments
    const v8s bq0 = *(const v8s*)(QU + (size_t)(q0 + l16) * DHD + quad * 8);
    const v8s bq1 = *(const v8s*)(QU + (size_t)(q0 + l16) * DHD + 32 + quad * 8);
    const v8s bv0 = *(const v8s*)(QV + (size_t)(q0 + l16) * DHD + quad * 8);
    const v8s bv1 = *(const v8s*)(QV + (size_t)(q0 + l16) * DHD + 32 + quad * 8);
    const v8s bw0 = *(const v8s*)(QV + (size_t)(q0 + 1 + l16) * DHD + quad * 8);
    const v8s bw1 = *(const v8s*)(QV + (size_t)(q0 + 1 + l16) * DHD + 32 + quad * 8);

    float m_run = -1e30f, l_run = 0.f;
    v4f accv[4];
#pragma unroll
    for (int r = 0; r < 4; ++r) accv[r] = (v4f){0.f, 0.f, 0.f, 0.f};
    const float scale = 0.04419417382415922f;

    for (int kt = 0; kt < 4; ++kt) {
        const int k0 = wave * 512 + kt * 128;

        // QK^T: C[key][q]
        v4f sacc[8];
#pragma unroll
        for (int nt = 0; nt < 8; ++nt) {
            v8s a0 = *(const v8s*)(Kg + (size_t)(k0 + nt * 16 + l16) * DHD + quad * 8);
            v8s a1 = *(const v8s*)(Kg + (size_t)(k0 + nt * 16 + l16) * DHD + 32 + quad * 8);
            v4f c = (v4f){0.f, 0.f, 0.f, 0.f};
            c = __builtin_amdgcn_mfma_f32_16x16x32_f16(a0, bq0, c, 0, 0, 0);
            c = __builtin_amdgcn_mfma_f32_16x16x32_f16(a1, bq1, c, 0, 0, 0);
            sacc[nt] = c;
        }

        // in-tile rel-shift GEMMs (wave-uniform predicates)
        const bool need1 = (k0 <= q0 + 15);
        const bool need2 = (k0 + 127 >= q0 + 2);
        if (need1) {
            const int J1 = 2032 - q0 + k0;
#pragma unroll
            for (int nr = 0; nr < 9; ++nr) {
                long row = (long)(J1 + nr * 16 + l16);
                v8s a0 = *(const v8s*)(Pb + row * DHD + quad * 8);
                v8s a1 = *(const v8s*)(Pb + row * DHD + 32 + quad * 8);
                v4f c = (v4f){0.f, 0.f, 0.f, 0.f};
                c = __builtin_amdgcn_mfma_f32_16x16x32_f16(a0, bv0, c, 0, 0, 0);
                c = __builtin_amdgcn_mfma_f32_16x16x32_f16(a1, bv1, c, 0, 0, 0);
                ushort4 pk;
                pk.x = f2h(c[0]); pk.y = f2h(c[1]); pk.z = f2h(c[2]); pk.w = f2h(c[3]);
                *(ushort4*)&R1L[l16 * 144 + nr * 16 + quad * 4] = pk;
            }
        }
        if (need2) {
            const int J2 = k0 - q0 - 17;
#pragma unroll
            for (int nr = 0; nr < 9; ++nr) {
                long row = (long)(J2 + nr * 16 + l16);
                v8s a0 = *(const v8s*)(Pb + row * DHD + quad * 8);
                v8s a1 = *(const v8s*)(Pb + row * DHD + 32 + quad * 8);
                v4f c = (v4f){0.f, 0.f, 0.f, 0.f};
                c = __builtin_amdgcn_mfma_f32_16x16x32_f16(a0, bw0, c, 0, 0, 0);
                c = __builtin_amdgcn_mfma_f32_16x16x32_f16(a1, bw1, c, 0, 0, 0);
                ushort4 pk;
                pk.x = f2h(c[0]); pk.y = f2h(c[1]); pk.z = f2h(c[2]); pk.w = f2h(c[3]);
                *(ushort4*)&R2L[l16 * 144 + nr * 16 + quad * 4] = pk;
            }
        }

        // extraction + scale + local max
        float tm = -1e30f;
#pragma unroll
        for (int nt = 0; nt < 8; ++nt) {
            int kb = k0 + nt * 16 + quad * 4;
            int iib = l16 * 144 + 15 - l16 + nt * 16 + quad * 4;
#pragma unroll
            for (int reg = 0; reg < 4; ++reg) {
                int dq = kb + reg - q;
                float pv;
                if (dq <= 0)      pv = h2f(R1L[iib + reg]);
                else if (dq == 1) pv = 0.f;
                else              pv = h2f(R2L[iib + reg]);
                sacc[nt][reg] = (sacc[nt][reg] + pv) * scale;
                tm = fmaxf(tm, sacc[nt][reg]);
            }
        }

        tm = fmaxf(tm, __shfl_xor(tm, 16));
        tm = fmaxf(tm, __shfl_xor(tm, 32));
        float mn = fmaxf(m_run, tm);
        float al = __expf(m_run - mn);
        float rs = 0.f;
#pragma unroll
        for (int nt = 0; nt < 8; ++nt)
#pragma unroll
            for (int reg = 0; reg < 4; ++reg) {
                sacc[nt][reg] = __expf(sacc[nt][reg] - mn);
                rs += sacc[nt][reg];
            }
        rs += __shfl_xor(rs, 16);
        rs += __shfl_xor(rs, 32);
        l_run = l_run * al + rs;
        m_run = mn;

        float alr[4];
#pragma unroll
        for (int reg = 0; reg < 4; ++reg) alr[reg] = __shfl(al, quad * 4 + reg);
#pragma unroll
        for (int ntd = 0; ntd < 4; ++ntd)
#pragma unroll
            for (int reg = 0; reg < 4; ++reg) accv[ntd][reg] *= alr[reg];

        // P -> Sp (aliases R1L; extraction reads already retired, in-order wave)
#pragma unroll
        for (int nt = 0; nt < 8; ++nt) {
            ushort4 pk;
            pk.x = f2h(sacc[nt][0]); pk.y = f2h(sacc[nt][1]);
            pk.z = f2h(sacc[nt][2]); pk.w = f2h(sacc[nt][3]);
            *(ushort4*)&Sp[l16 * 136 + nt * 16 + quad * 4] = pk;
        }

        // PV: A=P, B=V
#pragma unroll
        for (int c4 = 0; c4 < 4; ++c4) {
            v8s ap = *(const v8s*)&Sp[l16 * 136 + c4 * 32 + quad * 8];
#pragma unroll
            for (int ntd = 0; ntd < 4; ++ntd) {
                v8s bv8 = *(const v8s*)(Vg + (size_t)(ntd * 16 + l16) * S_LEN +
                                        k0 + c4 * 32 + quad * 8);
                accv[ntd] = __builtin_amdgcn_mfma_f32_16x16x32_f16(ap, bv8, accv[ntd], 0, 0, 0);
            }
        }
    }

    // split-K merge (4 waves): dump state, wave0 merges
    MlAll[wave][lane * 2]     = m_run;
    MlAll[wave][lane * 2 + 1] = l_run;
    if (wave != 0) {
        float* accSlot = (float*)&RAll[wave][0];
#pragma unroll
        for (int ntd = 0; ntd < 4; ++ntd)
#pragma unroll
            for (int reg = 0; reg < 4; ++reg)
                accSlot[lane * 16 + ntd * 4 + reg] = accv[ntd][reg];
    }
    __syncthreads();
    if (wave == 0) {
        const int bb = z >> 3, h = z & 7;
        float ew[4][4], inv[4];
#pragma unroll
        for (int reg = 0; reg < 4; ++reg) {
            int qi = quad * 4 + reg;
            float mw[4], lw[4];
#pragma unroll
            for (int w = 0; w < 4; ++w) {
                mw[w] = MlAll[w][qi * 2];
                lw[w] = MlAll[w][qi * 2 + 1];
            }
            float ms = fmaxf(fmaxf(mw[0], mw[1]), fmaxf(mw[2], mw[3]));
            float lt = 0.f;
#pragma unroll
            for (int w = 0; w < 4; ++w) {
                ew[reg][w] = __expf(mw[w] - ms);
                lt += lw[w] * ew[reg][w];
            }
            inv[reg] = 1.f / lt;
        }
#pragma unroll
        for (int ntd = 0; ntd < 4; ++ntd) {
#pragma unroll
            for (int reg = 0; reg < 4; ++reg) {
                float o = accv[ntd][reg] * ew[reg][0];
#pragma unroll
                for (int w = 1; w < 4; ++w) {
                    const float* slot = (const float*)&RAll[w][0];
                    o += slot[lane * 16 + ntd * 4 + reg] * ew[reg][w];
                }
                int qq = q0 + quad * 4 + reg;
                ctx[((size_t)(bb * S_LEN + qq)) * DM + h * DHD + ntd * 16 + l16] =
                    f2h(o * inv[reg]);
            }
        }
    }
}

// ---------------------------------------------------------------------------
// out_mfma: out(fp32)[s][n] = ctx(fp16) @ Wo + bo.  SWAPPED: C[n][s] ->
// float4 stores.  grid (32, 4): x = s-tile(128), y = n-tile(128).
// ---------------------------------------------------------------------------
__global__ __launch_bounds__(256)
void out_mfma(const float* __restrict__ bo, const char* __restrict__ wsb,
              float* __restrict__ out)
{
    const int t = threadIdx.x;
    const int wave = t >> 6, lane = t & 63;
    const int quad = lane >> 4, l16 = lane & 15;
    const int wm = wave >> 1, wn = wave & 1;
    const int n0 = blockIdx.y * 128 + wm * 64;
    const int s0 = blockIdx.x * 128 + wn * 64;
    const unsigned short* A = (const unsigned short*)(wsb + BY_WT) + (size_t)4 * WT_MAT_HALFS;
    const unsigned short* B = (const unsigned short*)(wsb + BY_CTX);

    v4f acc[4][4];
#pragma unroll
    for (int i = 0; i < 4; ++i)
#pragma unroll
        for (int j = 0; j < 4; ++j) acc[i][j] = (v4f){0.f, 0.f, 0.f, 0.f};

    for (int kk = 0; kk < 16; ++kk) {
        v8s af[4], bf[4];
#pragma unroll
        for (int i = 0; i < 4; ++i) {
            af[i] = *(const v8s*)(A + (size_t)(n0 + i * 16 + l16) * 512 + kk * 32 + quad * 8);
            bf[i] = *(const v8s*)(B + (size_t)(s0 + i * 16 + l16) * 512 + kk * 32 + quad * 8);
        }
#pragma unroll
        for (int i = 0; i < 4; ++i)
#pragma unroll
            for (int j = 0; j < 4; ++j)
                acc[i][j] = __builtin_amdgcn_mfma_f32_16x16x32_f16(af[i], bf[j], acc[i][j], 0, 0, 0);
    }

#pragma unroll
    for (int i = 0; i < 4; ++i) {
        int nb = n0 + i * 16 + quad * 4;
        float4 b4 = *(const float4*)(bo + nb);
#pragma unroll
        for (int j = 0; j < 4; ++j) {
            int s = s0 + j * 16 + l16;
            *(float4*)(out + (size_t)s * DM + nb) =
                make_float4(acc[i][j][0] + b4.x, acc[i][j][1] + b4.y,
                            acc[i][j][2] + b4.z, acc[i][j][3] + b4.w);
        }
    }
}

// Fallback when ws_size is insufficient: clean mismatch instead of OOB writes.
__global__ void zero_fill(float* __restrict__ p, int n)
{
    int i = blockIdx.x * 256 + threadIdx.x;
    if (i < n) p[i] = 0.f;
}

// ---------------------------------------------------------------------------
extern "C" void kernel_launch(void* const* d_in, const int* in_sizes, int n_in,
                              void* d_out, int out_size, void* d_ws, size_t ws_size,
                              hipStream_t stream)
{
    const float* x   = (const float*)d_in[0];
    const float* pos = (const float*)d_in[1];
    const float* Wq  = (const float*)d_in[2];
    const float* bq  = (const float*)d_in[3];
    const float* Wk  = (const float*)d_in[4];
    const float* bk  = (const float*)d_in[5];
    const float* Wv  = (const float*)d_in[6];
    const float* bv  = (const float*)d_in[7];
    const float* Wp  = (const float*)d_in[8];
    const float* u   = (const float*)d_in[9];
    const float* v   = (const float*)d_in[10];
    const float* Wo  = (const float*)d_in[11];
    const float* bo  = (const float*)d_in[12];
    char* wsb  = (char*)d_ws;
    float* out = (float*)d_out;

    if (ws_size < (size_t)WS_NEED) {
        zero_fill<<<(out_size + 255) / 256, 256, 0, stream>>>(out, out_size);
        return;
    }

    // 1. dtype prep
    conv_inputs<<<dim3(2048, 1, 2), 256, 0, stream>>>(x, pos, wsb);
    conv_wt<<<dim3(8, 8, 5), 256, 0, stream>>>(Wq, Wk, Wv, Wp, Wo, wsb);

    // 2. projections (fp16 MFMA)
    proj_mfma<<<dim3(32, 4, 4), 256, 0, stream>>>(bq, bk, bv, u, v, wsb);

    // 3. fused attention, all heads in one launch
    attn_fused<<<dim3(NBH * 128), 256, 0, stream>>>(
        (const unsigned short*)(wsb + BY_QU),
        (const unsigned short*)(wsb + BY_QV),
        (const unsigned short*)(wsb + BY_K),
        (const unsigned short*)(wsb + BY_VT),
        (const unsigned short*)(wsb + BY_PB),
        (unsigned short*)(wsb + BY_CTX));

    // 4. output projection (fp16 MFMA, fp32 out)
    out_mfma<<<dim3(32, 4), 256, 0, stream>>>(bo, wsb, out);
}